// Round 11
// baseline (708.425 us; speedup 1.0000x reference)
//
#include <hip/hip_runtime.h>
#include <math.h>

#define NN 20000
#define NE 160000
#define NG 1000
#define IND 11
#define H 128
#define ED 3
#define NL 5
#define ZDH (259*128)
#define BN_EPSF 1e-5f

typedef unsigned short ushort_t;
typedef __attribute__((ext_vector_type(8))) short bf8_t;
typedef __attribute__((ext_vector_type(4))) float f4_t;

__device__ inline ushort_t f2bf(float x) {
    unsigned int u = __float_as_uint(x);
    unsigned int r = (u + 0x7fffu + ((u >> 16) & 1u)) >> 16;
    return (ushort_t)r;
}
__device__ inline float bf2f(ushort_t b) {
    return __uint_as_float(((unsigned int)b) << 16);
}

// ---------------- CSR build (once per call) ----------------

__global__ void deg_int_kernel(const int* __restrict__ dst, int* __restrict__ degi) {
    int e = blockIdx.x * blockDim.x + threadIdx.x;
    if (e < NE) atomicAdd(&degi[dst[e]], 1);
}

__global__ __launch_bounds__(256) void reserve_kernel(const int* __restrict__ degi,
                                                      int* __restrict__ cursor,
                                                      float* __restrict__ invdeg,
                                                      int* __restrict__ counter) {
    int n = blockIdx.x * blockDim.x + threadIdx.x;
    int lane = threadIdx.x & 63;
    int v = (n < NN) ? degi[n] : 0;
    int x = v;
#pragma unroll
    for (int st = 1; st < 64; st <<= 1) {
        int y = __shfl_up(x, st, 64);
        if (lane >= st) x += y;
    }
    int total = __shfl(x, 63, 64);
    int base = 0;
    if (lane == 63) base = atomicAdd(counter, total);
    base = __shfl(base, 63, 64);
    if (n < NN) {
        cursor[n] = base + x - v;
        invdeg[n] = 1.0f / (float)(v < 1 ? 1 : v);
    }
}

__global__ void scatter_kernel(const int* __restrict__ src, const int* __restrict__ dst,
                               const float* __restrict__ ea,
                               int* __restrict__ cursor, float4* __restrict__ csr_ea4,
                               int* __restrict__ csr_dst) {
    int e = blockIdx.x * blockDim.x + threadIdx.x;
    if (e < NE) {
        int d = dst[e];
        int pos = atomicAdd(&cursor[d], 1);
        float4 r;
        r.x = ea[e * ED + 0];
        r.y = ea[e * ED + 1];
        r.z = ea[e * ED + 2];
        r.w = __int_as_float(src[e]);
        csr_ea4[pos] = r;
        csr_dst[pos] = d;
    }
}

// ---------------- weight prep: transpose to [n][k] bf16 hi/lo ----------------
// table order: 0=Pf(Wf k<128), 1=Ps(Ws k<128), 2=Qf(Wf k>=128), 3=Qs(Ws k>=128)
__global__ void wprep_kernel(const float* __restrict__ Wf, const float* __restrict__ Ws,
                             ushort_t* __restrict__ Wt_hi, ushort_t* __restrict__ Wt_lo) {
    int idx = blockIdx.x * 256 + threadIdx.x;   // l*65536 + n*128 + k
    if (idx >= NL * 512 * H) return;
    int k = idx & 127;
    int n = (idx >> 7) & 511;
    int l = idx >> 16;
    int t = n >> 7, j = n & 127;
    const float* W = (t == 0 || t == 2) ? Wf : Ws;
    int krow = (t < 2) ? k : (H + k);
    float v = W[(size_t)l * ZDH + krow * H + j];
    ushort_t hi = f2bf(v);
    Wt_hi[idx] = hi;
    Wt_lo[idx] = f2bf(v - bf2f(hi));
}

// ---------------- network ----------------

__global__ __launch_bounds__(H) void hin_kernel(const float* __restrict__ x,
                                                const float* __restrict__ Win,
                                                const float* __restrict__ bin,
                                                float* __restrict__ h) {
    int n = blockIdx.x;
    int j = threadIdx.x;
    __shared__ float xr[IND];
    if (j < IND) xr[j] = x[n * IND + j];
    __syncthreads();
    float acc = bin[j];
#pragma unroll
    for (int k = 0; k < IND; ++k) acc = fmaf(xr[k], Win[k * H + j], acc);
    h[(size_t)n * H + j] = acc;
}

// MFMA node GEMM v4: planar outputs (coalesced C-writes), 64-row blocks.
// grid = (ceil(NN/64), 4 tables); block = 4 waves, wave owns 16 rows.
// Fused BN_{l-1}+ReLU on the A path; table-0 blocks also write post-BN fp32 h.
// Output plane t: tabs[t][row*128 + col], col = nt*16+sub (stride-1 across lanes).
__global__ __launch_bounds__(256) void node_gemm_mfma(const float* __restrict__ hsrc,
                                                      float* __restrict__ hbn,
                                                      const ushort_t* __restrict__ Wt_hi,
                                                      const ushort_t* __restrict__ Wt_lo,
                                                      const float* __restrict__ sum,
                                                      const float* __restrict__ sumsq,
                                                      const float* __restrict__ gamma,
                                                      const float* __restrict__ beta,
                                                      int applyBN,
                                                      float* __restrict__ tab0,
                                                      float* __restrict__ tab1,
                                                      float* __restrict__ tab2,
                                                      float* __restrict__ tab3) {
    int table = blockIdx.y;
    int wave = threadIdx.x >> 6;
    int lane = threadIdx.x & 63;
    int sub = lane & 15;
    int quad = lane >> 4;
    int m0 = blockIdx.x * 64 + wave * 16;
    int writeH = applyBN && (table == 0);

    const ushort_t* wh = Wt_hi + (size_t)table * 128 * H;
    const ushort_t* wl = Wt_lo + (size_t)table * 128 * H;

    // ---- A staging: fp32 h -> optional BN+ReLU -> bf16 hi/lo ----
    bf8_t aHi[4], aLo[4];
    int r = m0 + sub;
    int rc = r < NN ? r : NN - 1;
#pragma unroll
    for (int ks = 0; ks < 4; ++ks) {
        int kb = ks * 32 + quad * 8;
        const float* hp = hsrc + (size_t)rc * H + kb;
        float4 v0 = *(const float4*)hp;
        float4 v1 = *(const float4*)(hp + 4);
        float vv[8] = {v0.x, v0.y, v0.z, v0.w, v1.x, v1.y, v1.z, v1.w};
        if (applyBN) {
            float4 su0 = *(const float4*)&sum[kb],   su1 = *(const float4*)&sum[kb + 4];
            float4 sq0 = *(const float4*)&sumsq[kb], sq1 = *(const float4*)&sumsq[kb + 4];
            float4 ga0 = *(const float4*)&gamma[kb], ga1 = *(const float4*)&gamma[kb + 4];
            float4 be0 = *(const float4*)&beta[kb],  be1 = *(const float4*)&beta[kb + 4];
            float su[8] = {su0.x, su0.y, su0.z, su0.w, su1.x, su1.y, su1.z, su1.w};
            float sq[8] = {sq0.x, sq0.y, sq0.z, sq0.w, sq1.x, sq1.y, sq1.z, sq1.w};
            float ga[8] = {ga0.x, ga0.y, ga0.z, ga0.w, ga1.x, ga1.y, ga1.z, ga1.w};
            float be[8] = {be0.x, be0.y, be0.z, be0.w, be1.x, be1.y, be1.z, be1.w};
#pragma unroll
            for (int i = 0; i < 8; ++i) {
                float mu  = su[i] * (1.0f / NN);
                float var = sq[i] * (1.0f / NN) - mu * mu;
                float sc  = ga[i] * rsqrtf(var + BN_EPSF);
                float sh  = be[i] - mu * sc;
                float v = fmaf(vv[i], sc, sh);
                vv[i] = v > 0.0f ? v : 0.0f;
            }
        }
        bf8_t hi8, lo8;
#pragma unroll
        for (int i = 0; i < 8; ++i) {
            ushort_t hi = f2bf(vv[i]);
            hi8[i] = (short)hi;
            lo8[i] = (short)f2bf(vv[i] - bf2f(hi));
        }
        aHi[ks] = hi8;
        aLo[ks] = lo8;
        if (writeH && r < NN) {
            float* op = hbn + (size_t)r * H + kb;
            *(float4*)op = make_float4(vv[0], vv[1], vv[2], vv[3]);
            *(float4*)(op + 4) = make_float4(vv[4], vv[5], vv[6], vv[7]);
        }
    }

    f4_t acc[8];
#pragma unroll
    for (int b = 0; b < 8; ++b) acc[b] = (f4_t){0.f, 0.f, 0.f, 0.f};

    bf8_t bHi[4], bLo[4];
#pragma unroll
    for (int ks = 0; ks < 4; ++ks) {
        size_t bo = (size_t)sub * H + ks * 32 + quad * 8;
        bHi[ks] = *(const bf8_t*)(wh + bo);
        bLo[ks] = *(const bf8_t*)(wl + bo);
    }

#pragma unroll
    for (int nt = 0; nt < 8; ++nt) {
        bf8_t nHi[4], nLo[4];
        if (nt < 7) {
#pragma unroll
            for (int ks = 0; ks < 4; ++ks) {
                size_t bo = (size_t)((nt + 1) * 16 + sub) * H + ks * 32 + quad * 8;
                nHi[ks] = *(const bf8_t*)(wh + bo);
                nLo[ks] = *(const bf8_t*)(wl + bo);
            }
        }
#pragma unroll
        for (int ks = 0; ks < 4; ++ks) {
            acc[nt] = __builtin_amdgcn_mfma_f32_16x16x32_bf16(aHi[ks], bHi[ks], acc[nt], 0, 0, 0);
            acc[nt] = __builtin_amdgcn_mfma_f32_16x16x32_bf16(aLo[ks], bHi[ks], acc[nt], 0, 0, 0);
            acc[nt] = __builtin_amdgcn_mfma_f32_16x16x32_bf16(aHi[ks], bLo[ks], acc[nt], 0, 0, 0);
        }
#pragma unroll
        for (int ks = 0; ks < 4; ++ks) { bHi[ks] = nHi[ks]; bLo[ks] = nLo[ks]; }
    }

    float* outp = (table == 0) ? tab0 : (table == 1) ? tab1 : (table == 2) ? tab2 : tab3;
#pragma unroll
    for (int nt = 0; nt < 8; ++nt) {
        int col = nt * 16 + sub;
#pragma unroll
        for (int rr = 0; rr < 4; ++rr) {
            int row = m0 + quad * 4 + rr;
            if (row < NN) outp[(size_t)row * H + col] = acc[nt][rr];
        }
    }
}

// Edge-parallel segmented CSR aggregation over planar tables.
// Wave owns 32 consecutive CSR positions; lane owns cols (2l,2l+1).
// Pf/Ps[dst] loaded once per segment (next-segment prefetch); Qf/Qs[src] in
// an 8-deep rolling window. Flush = atomicAdd into residual base h.
__global__ __launch_bounds__(256) void agg_edge_kernel(const int4* __restrict__ csr_fe,
                                                       const int* __restrict__ csr_dst,
                                                       const float* __restrict__ Wf,
                                                       const float* __restrict__ bf,
                                                       const float* __restrict__ Ws,
                                                       const float* __restrict__ bs,
                                                       const float* __restrict__ tab0,
                                                       const float* __restrict__ tab1,
                                                       const float* __restrict__ tab2,
                                                       const float* __restrict__ tab3,
                                                       const float* __restrict__ invdeg,
                                                       float* __restrict__ h,
                                                       float* __restrict__ sum,
                                                       float* __restrict__ sumsq) {
    int tid = threadIdx.x;
    if (blockIdx.x == 0 && tid < H) { sum[tid] = 0.0f; sumsq[tid] = 0.0f; }
    int lane = tid & 63;
    int wv = tid >> 6;
    int base = (blockIdx.x * 4 + wv) * 32;
    int c0 = 2 * lane;

    const float2* Pf2 = (const float2*)tab0;
    const float2* Ps2 = (const float2*)tab1;
    const float2* Qf2 = (const float2*)tab2;
    const float2* Qs2 = (const float2*)tab3;

    float2 wf0 = *(const float2*)&Wf[256 * H + c0];
    float2 wf1 = *(const float2*)&Wf[257 * H + c0];
    float2 wf2 = *(const float2*)&Wf[258 * H + c0];
    float2 ws0 = *(const float2*)&Ws[256 * H + c0];
    float2 ws1 = *(const float2*)&Ws[257 * H + c0];
    float2 ws2 = *(const float2*)&Ws[258 * H + c0];
    float2 bf2_ = *(const float2*)&bf[c0];
    float2 bs2_ = *(const float2*)&bs[c0];

    int4 fe = csr_fe[base + (lane & 31)];
    int  dd = csr_dst[base + (lane & 31)];

    float2 qf[8], qs[8];
#pragma unroll
    for (int i = 0; i < 8; ++i) {
        int s = __builtin_amdgcn_readlane(fe.w, i);
        qf[i] = Qf2[(size_t)s * 64 + lane];
        qs[i] = Qs2[(size_t)s * 64 + lane];
    }

    int dcur = __builtin_amdgcn_readlane(dd, 0);
    float2 pfCur = Pf2[(size_t)dcur * 64 + lane];
    float2 psCur = Ps2[(size_t)dcur * 64 + lane];
    int tNext = 1;
    while (tNext < 32 && __builtin_amdgcn_readlane(dd, tNext) == dcur) ++tNext;
    int dNext = (tNext < 32) ? __builtin_amdgcn_readlane(dd, tNext) : 0;
    float2 pfNext = Pf2[(size_t)dNext * 64 + lane];
    float2 psNext = Ps2[(size_t)dNext * 64 + lane];

    float acc0 = 0.f, acc1 = 0.f;

#pragma unroll
    for (int tb = 0; tb < 32; tb += 8) {
#pragma unroll
        for (int i = 0; i < 8; ++i) {
            int t = tb + i;
            if (t == tNext) {   // wave-uniform segment boundary
                float inv = invdeg[dcur];
                atomicAdd(&h[(size_t)dcur * H + c0], acc0 * inv);
                atomicAdd(&h[(size_t)dcur * H + c0 + 1], acc1 * inv);
                acc0 = 0.f; acc1 = 0.f;
                dcur = dNext;
                pfCur = pfNext;
                psCur = psNext;
                int ts = t + 1;
                while (ts < 32 && __builtin_amdgcn_readlane(dd, ts) == dcur) ++ts;
                tNext = ts;
                if (ts < 32) {
                    dNext = __builtin_amdgcn_readlane(dd, ts);
                    pfNext = Pf2[(size_t)dNext * 64 + lane];
                    psNext = Ps2[(size_t)dNext * 64 + lane];
                }
            }
            float ex = __int_as_float(__builtin_amdgcn_readlane(fe.x, t));
            float ey = __int_as_float(__builtin_amdgcn_readlane(fe.y, t));
            float ez = __int_as_float(__builtin_amdgcn_readlane(fe.z, t));
            float2 qqf = qf[i], qqs = qs[i];
            if (t + 8 < 32) {
                int s2 = __builtin_amdgcn_readlane(fe.w, t + 8);
                qf[i] = Qf2[(size_t)s2 * 64 + lane];
                qs[i] = Qs2[(size_t)s2 * 64 + lane];
            }
            float f0 = fmaf(ex, wf0.x, fmaf(ey, wf1.x, fmaf(ez, wf2.x, pfCur.x + bf2_.x + qqf.x)));
            float v0 = fmaf(ex, ws0.x, fmaf(ey, ws1.x, fmaf(ez, ws2.x, psCur.x + bs2_.x + qqs.x)));
            float f1 = fmaf(ex, wf0.y, fmaf(ey, wf1.y, fmaf(ez, wf2.y, pfCur.y + bf2_.y + qqf.y)));
            float v1 = fmaf(ex, ws0.y, fmaf(ey, ws1.y, fmaf(ez, ws2.y, psCur.y + bs2_.y + qqs.y)));
            float sig0 = __builtin_amdgcn_rcpf(1.0f + __expf(-f0));
            float sp0  = fmaxf(v0, 0.0f) + __logf(1.0f + __expf(-fabsf(v0)));
            float sig1 = __builtin_amdgcn_rcpf(1.0f + __expf(-f1));
            float sp1  = fmaxf(v1, 0.0f) + __logf(1.0f + __expf(-fabsf(v1)));
            acc0 = fmaf(sig0, sp0, acc0);
            acc1 = fmaf(sig1, sp1, acc1);
        }
    }
    float inv = invdeg[dcur];
    atomicAdd(&h[(size_t)dcur * H + c0], acc0 * inv);
    atomicAdd(&h[(size_t)dcur * H + c0 + 1], acc1 * inv);
}

// per-column sum / sumsq; 4 independent row loads per iteration.
__global__ __launch_bounds__(H) void stats_kernel(const float* __restrict__ h,
                                                  float* __restrict__ sum,
                                                  float* __restrict__ sumsq) {
    int j = threadIdx.x;
    float s = 0.0f, ss = 0.0f;
    int n = blockIdx.x * 4;
    for (; n + 3 < NN; n += gridDim.x * 4) {
        float v0 = h[(size_t)(n + 0) * H + j];
        float v1 = h[(size_t)(n + 1) * H + j];
        float v2 = h[(size_t)(n + 2) * H + j];
        float v3 = h[(size_t)(n + 3) * H + j];
        s += (v0 + v1) + (v2 + v3);
        ss = fmaf(v0, v0, ss); ss = fmaf(v1, v1, ss);
        ss = fmaf(v2, v2, ss); ss = fmaf(v3, v3, ss);
    }
    for (; n < NN; ++n) {
        float v = h[(size_t)n * H + j];
        s += v;
        ss = fmaf(v, v, ss);
    }
    atomicAdd(&sum[j], s);
    atomicAdd(&sumsq[j], ss);
}

__global__ __launch_bounds__(H) void pool_kernel(const float* __restrict__ h,
                                                 const int* __restrict__ batch,
                                                 const float* __restrict__ sum,
                                                 const float* __restrict__ sumsq,
                                                 const float* __restrict__ gamma,
                                                 const float* __restrict__ beta,
                                                 float* __restrict__ g,
                                                 float* __restrict__ cnt) {
    int j = threadIdx.x;
    float mu  = sum[j] * (1.0f / NN);
    float var = sumsq[j] * (1.0f / NN) - mu * mu;
    float sc  = gamma[j] * rsqrtf(var + BN_EPSF);
    float sh  = beta[j] - mu * sc;
    for (int n = blockIdx.x; n < NN; n += gridDim.x) {
        int b = batch[n];
        float v = fmaf(h[(size_t)n * H + j], sc, sh);
        v = v > 0.0f ? v : 0.0f;
        atomicAdd(&g[(size_t)b * H + j], v);
        if (j == 0) atomicAdd(&cnt[b], 1.0f);
    }
}

__global__ __launch_bounds__(H) void mlp_kernel(const float* __restrict__ g,
                                                const float* __restrict__ cnt,
                                                const float* __restrict__ W1,
                                                const float* __restrict__ b1,
                                                const float* __restrict__ W2,
                                                const float* __restrict__ b2,
                                                const float* __restrict__ W3,
                                                const float* __restrict__ b3,
                                                float* __restrict__ out) {
    int gid = blockIdx.x, j = threadIdx.x;
    __shared__ float s1[H];
    __shared__ float s2[H];
    __shared__ float wsum[2];
    float c = cnt[gid];
    c = c < 1.0f ? 1.0f : c;
    s1[j] = g[gid * H + j] / c;
    __syncthreads();
    float a = b1[j];
    for (int k = 0; k < H; ++k) a = fmaf(s1[k], W1[k * H + j], a);
    a = a > 0.0f ? a : 0.0f;
    s2[j] = a;
    __syncthreads();
    float t = b2[j];
    for (int k = 0; k < H; ++k) t = fmaf(s2[k], W2[k * H + j], t);
    t = t > 0.0f ? t : 0.0f;
    float p = t * W3[j];
    for (int off = 32; off > 0; off >>= 1) p += __shfl_down(p, off, 64);
    if ((j & 63) == 0) wsum[j >> 6] = p;
    __syncthreads();
    if (j == 0) out[gid] = wsum[0] + wsum[1] + b3[0];
}

extern "C" void kernel_launch(void* const* d_in, const int* in_sizes, int n_in,
                              void* d_out, int out_size, void* d_ws, size_t ws_size,
                              hipStream_t stream) {
    const float* x     = (const float*)d_in[0];
    const int*   ei    = (const int*)d_in[1];
    const int*   srcp  = ei;        // edge_index[0] = source (x_j)
    const int*   dstp  = ei + NE;   // edge_index[1] = target (aggregation index)
    const int*   batch = (const int*)d_in[2];
    const float* ea    = (const float*)d_in[3];
    const float* Win   = (const float*)d_in[4];
    const float* bin   = (const float*)d_in[5];
    const float* Wf    = (const float*)d_in[6];
    const float* bf    = (const float*)d_in[7];
    const float* Ws    = (const float*)d_in[8];
    const float* bs    = (const float*)d_in[9];
    const float* gamma = (const float*)d_in[10];
    const float* beta  = (const float*)d_in[11];
    const float* W1    = (const float*)d_in[12];
    const float* b1    = (const float*)d_in[13];
    const float* W2    = (const float*)d_in[14];
    const float* b2    = (const float*)d_in[15];
    const float* W3    = (const float*)d_in[16];
    const float* b3    = (const float*)d_in[17];
    float* out = (float*)d_out;

    const size_t NH = (size_t)NN * H;
    float* wsp = (float*)d_ws;
    size_t off = 0;
    float* hA     = wsp + off; off += NH;
    float* hB     = wsp + off; off += NH;
    float* tab0   = wsp + off; off += NH;   // Pf
    float* tab1   = wsp + off; off += NH;   // Ps
    float* tab2   = wsp + off; off += NH;   // Qf
    float* tab3   = wsp + off; off += NH;   // Qs
    float* invdeg = wsp + off; off += NN;
    float* sum    = wsp + off; off += H;
    float* sumsq  = wsp + off; off += H;
    float* g      = wsp + off; off += (size_t)NG * H;
    float* cnt    = wsp + off; off += NG;
    off = (off + 3) & ~(size_t)3;
    float4* csr_ea4 = (float4*)(wsp + off); off += (size_t)NE * 4;
    int* degi      = (int*)(wsp + off); off += NN;
    int* counter   = (int*)(wsp + off); off += 1;
    int* cursor    = (int*)(wsp + off); off += NN;
    int* csr_dst   = (int*)(wsp + off); off += NE;
    off = (off + 3) & ~(size_t)3;
    ushort_t* Wt_hi = (ushort_t*)(wsp + off); off += (size_t)NL * 512 * H / 2;
    ushort_t* Wt_lo = (ushort_t*)(wsp + off); off += (size_t)NL * 512 * H / 2;

    // ---- CSR + weight prep (topology/weights fixed across layers) ----
    hipMemsetAsync(degi, 0, (NN + 1) * sizeof(int), stream);  // degi + counter
    deg_int_kernel<<<(NE + 255) / 256, 256, 0, stream>>>(dstp, degi);
    reserve_kernel<<<(NN + 255) / 256, 256, 0, stream>>>(degi, cursor, invdeg, counter);
    scatter_kernel<<<(NE + 255) / 256, 256, 0, stream>>>(srcp, dstp, ea, cursor, csr_ea4, csr_dst);
    wprep_kernel<<<(NL * 512 * H + 255) / 256, 256, 0, stream>>>(Wf, Ws, Wt_hi, Wt_lo);

    hin_kernel<<<NN, H, 0, stream>>>(x, Win, bin, hA);

    // ping-pong: layer 0 aggregates into hA (raw h0); layer l>=1's gemm reads
    // the previous target, writes post-BN h into the other buffer, which then
    // receives that layer's aggregation.
    float* hRead = hA;
    for (int l = 0; l < NL; ++l) {
        float* hTgt = (l == 0) ? hA : ((l & 1) ? hB : hA);
        node_gemm_mfma<<<dim3((NN + 63) / 64, 4), 256, 0, stream>>>(
            hRead, hTgt,
            Wt_hi + (size_t)l * 512 * H,
            Wt_lo + (size_t)l * 512 * H,
            sum, sumsq,
            gamma + (size_t)(l ? l - 1 : 0) * H,
            beta  + (size_t)(l ? l - 1 : 0) * H,
            l > 0, tab0, tab1, tab2, tab3);
        agg_edge_kernel<<<NE / 128, 256, 0, stream>>>((const int4*)csr_ea4, csr_dst,
                                                      Wf + (size_t)l * ZDH, bf + (size_t)l * H,
                                                      Ws + (size_t)l * ZDH, bs + (size_t)l * H,
                                                      tab0, tab1, tab2, tab3,
                                                      invdeg, hTgt, sum, sumsq);
        stats_kernel<<<512, H, 0, stream>>>(hTgt, sum, sumsq);
        hRead = hTgt;
    }

    hipMemsetAsync(g, 0, ((size_t)NG * H + NG) * sizeof(float), stream);
    pool_kernel<<<2048, H, 0, stream>>>(hRead, batch, sum, sumsq,
                                        gamma + (size_t)(NL - 1) * H,
                                        beta + (size_t)(NL - 1) * H, g, cnt);
    mlp_kernel<<<NG, H, 0, stream>>>(g, cnt, W1, b1, W2, b2, W3, b3, out);
}

// Round 12
// 546.232 us; speedup vs baseline: 1.2969x; 1.2969x over previous
//
#include <hip/hip_runtime.h>
#include <math.h>

#define NN 20000
#define NE 160000
#define NG 1000
#define IND 11
#define H 128
#define ED 3
#define NL 5
#define ZDH (259*128)
#define BN_EPSF 1e-5f
#define BPAD 17   /* 16B-chunks per B-row in LDS (16 + 1 pad) */

typedef unsigned short ushort_t;
typedef __attribute__((ext_vector_type(8))) short bf8_t;
typedef __attribute__((ext_vector_type(4))) float f4_t;

__device__ inline ushort_t f2bf(float x) {
    unsigned int u = __float_as_uint(x);
    unsigned int r = (u + 0x7fffu + ((u >> 16) & 1u)) >> 16;
    return (ushort_t)r;
}
__device__ inline float bf2f(ushort_t b) {
    return __uint_as_float(((unsigned int)b) << 16);
}

// ---------------- CSR build (once per call) ----------------

__global__ void deg_int_kernel(const int* __restrict__ dst, int* __restrict__ degi) {
    int e = blockIdx.x * blockDim.x + threadIdx.x;
    if (e < NE) atomicAdd(&degi[dst[e]], 1);
}

__global__ __launch_bounds__(256) void reserve_kernel(const int* __restrict__ degi,
                                                      int* __restrict__ cursor,
                                                      float* __restrict__ invdeg,
                                                      int* __restrict__ counter) {
    int n = blockIdx.x * blockDim.x + threadIdx.x;
    int lane = threadIdx.x & 63;
    int v = (n < NN) ? degi[n] : 0;
    int x = v;
#pragma unroll
    for (int st = 1; st < 64; st <<= 1) {
        int y = __shfl_up(x, st, 64);
        if (lane >= st) x += y;
    }
    int total = __shfl(x, 63, 64);
    int base = 0;
    if (lane == 63) base = atomicAdd(counter, total);
    base = __shfl(base, 63, 64);
    if (n < NN) {
        cursor[n] = base + x - v;
        invdeg[n] = 1.0f / (float)(v < 1 ? 1 : v);
    }
}

__global__ void scatter_kernel(const int* __restrict__ src, const int* __restrict__ dst,
                               const float* __restrict__ ea,
                               int* __restrict__ cursor, float4* __restrict__ csr_ea4,
                               int* __restrict__ csr_dst) {
    int e = blockIdx.x * blockDim.x + threadIdx.x;
    if (e < NE) {
        int d = dst[e];
        int pos = atomicAdd(&cursor[d], 1);
        float4 r;
        r.x = ea[e * ED + 0];
        r.y = ea[e * ED + 1];
        r.z = ea[e * ED + 2];
        r.w = __int_as_float(src[e]);
        csr_ea4[pos] = r;
        csr_dst[pos] = d;
    }
}

// ---------------- weight prep: transpose to [n][k] bf16 hi/lo ----------------
// table order: 0=Pf(Wf k<128), 1=Ps(Ws k<128), 2=Qf(Wf k>=128), 3=Qs(Ws k>=128)
__global__ void wprep_kernel(const float* __restrict__ Wf, const float* __restrict__ Ws,
                             ushort_t* __restrict__ Wt_hi, ushort_t* __restrict__ Wt_lo) {
    int idx = blockIdx.x * 256 + threadIdx.x;   // l*65536 + n*128 + k
    if (idx >= NL * 512 * H) return;
    int k = idx & 127;
    int n = (idx >> 7) & 511;
    int l = idx >> 16;
    int t = n >> 7, j = n & 127;
    const float* W = (t == 0 || t == 2) ? Wf : Ws;
    int krow = (t < 2) ? k : (H + k);
    float v = W[(size_t)l * ZDH + krow * H + j];
    ushort_t hi = f2bf(v);
    Wt_hi[idx] = hi;
    Wt_lo[idx] = f2bf(v - bf2f(hi));
}

// ---------------- network ----------------

__global__ __launch_bounds__(H) void hin_kernel(const float* __restrict__ x,
                                                const float* __restrict__ Win,
                                                const float* __restrict__ bin,
                                                float* __restrict__ h) {
    int n = blockIdx.x;
    int j = threadIdx.x;
    __shared__ float xr[IND];
    if (j < IND) xr[j] = x[n * IND + j];
    __syncthreads();
    float acc = bin[j];
#pragma unroll
    for (int k = 0; k < IND; ++k) acc = fmaf(xr[k], Win[k * H + j], acc);
    h[(size_t)n * H + j] = acc;
}

// MFMA node GEMM v5: B staged in LDS once per block (kills per-wave B re-read
// from L2, the R10/R11 limiter). grid = (ceil(NN/128), 4 tables); 4 waves,
// wave owns 32 rows. Planar coalesced C-writes; fused BN_{l-1}+ReLU on A path;
// table-0 blocks also write post-BN fp32 h.
__global__ __launch_bounds__(256, 2) void node_gemm_mfma(const float* __restrict__ hsrc,
                                                         float* __restrict__ hbn,
                                                         const ushort_t* __restrict__ Wt_hi,
                                                         const ushort_t* __restrict__ Wt_lo,
                                                         const float* __restrict__ sum,
                                                         const float* __restrict__ sumsq,
                                                         const float* __restrict__ gamma,
                                                         const float* __restrict__ beta,
                                                         int applyBN,
                                                         float* __restrict__ tab0,
                                                         float* __restrict__ tab1,
                                                         float* __restrict__ tab2,
                                                         float* __restrict__ tab3) {
    __shared__ __align__(16) ushort_t lbHi[128 * BPAD * 8];  // 34816 B
    __shared__ __align__(16) ushort_t lbLo[128 * BPAD * 8];  // 34816 B
    int table = blockIdx.y;
    int wave = threadIdx.x >> 6;
    int lane = threadIdx.x & 63;
    int sub = lane & 15;
    int quad = lane >> 4;
    int m0 = blockIdx.x * 128 + wave * 32;
    int writeH = applyBN && (table == 0);

    const ushort_t* wh = Wt_hi + (size_t)table * 128 * H;
    const ushort_t* wl = Wt_lo + (size_t)table * 128 * H;

    // ---- stage B into LDS: 2048 16B-chunks per half, 8 iters/thread ----
    for (int c = threadIdx.x; c < 2048; c += 256) {
        int n = c >> 4, k = c & 15;
        bf8_t vh = *(const bf8_t*)(wh + n * H + k * 8);
        bf8_t vl = *(const bf8_t*)(wl + n * H + k * 8);
        *(bf8_t*)(lbHi + ((size_t)n * BPAD + k) * 8) = vh;
        *(bf8_t*)(lbLo + ((size_t)n * BPAD + k) * 8) = vl;
    }

    // ---- A staging: fp32 h -> optional BN+ReLU -> bf16 hi/lo (2 row-tiles) ----
    bf8_t aHi[2][4], aLo[2][4];
#pragma unroll
    for (int ks = 0; ks < 4; ++ks) {
        int kb = ks * 32 + quad * 8;
        float sc8[8], sh8[8];
        if (applyBN) {
            float4 su0 = *(const float4*)&sum[kb],   su1 = *(const float4*)&sum[kb + 4];
            float4 sq0 = *(const float4*)&sumsq[kb], sq1 = *(const float4*)&sumsq[kb + 4];
            float4 ga0 = *(const float4*)&gamma[kb], ga1 = *(const float4*)&gamma[kb + 4];
            float4 be0 = *(const float4*)&beta[kb],  be1 = *(const float4*)&beta[kb + 4];
            float su[8] = {su0.x, su0.y, su0.z, su0.w, su1.x, su1.y, su1.z, su1.w};
            float sq[8] = {sq0.x, sq0.y, sq0.z, sq0.w, sq1.x, sq1.y, sq1.z, sq1.w};
            float ga[8] = {ga0.x, ga0.y, ga0.z, ga0.w, ga1.x, ga1.y, ga1.z, ga1.w};
            float be[8] = {be0.x, be0.y, be0.z, be0.w, be1.x, be1.y, be1.z, be1.w};
#pragma unroll
            for (int i = 0; i < 8; ++i) {
                float mu  = su[i] * (1.0f / NN);
                float var = sq[i] * (1.0f / NN) - mu * mu;
                sc8[i] = ga[i] * rsqrtf(var + BN_EPSF);
                sh8[i] = be[i] - mu * sc8[i];
            }
        }
#pragma unroll
        for (int mt = 0; mt < 2; ++mt) {
            int r = m0 + mt * 16 + sub;
            int rc = r < NN ? r : NN - 1;
            const float* hp = hsrc + (size_t)rc * H + kb;
            float4 v0 = *(const float4*)hp;
            float4 v1 = *(const float4*)(hp + 4);
            float vv[8] = {v0.x, v0.y, v0.z, v0.w, v1.x, v1.y, v1.z, v1.w};
            if (applyBN) {
#pragma unroll
                for (int i = 0; i < 8; ++i) {
                    float v = fmaf(vv[i], sc8[i], sh8[i]);
                    vv[i] = v > 0.0f ? v : 0.0f;
                }
            }
            bf8_t hi8, lo8;
#pragma unroll
            for (int i = 0; i < 8; ++i) {
                ushort_t hi = f2bf(vv[i]);
                hi8[i] = (short)hi;
                lo8[i] = (short)f2bf(vv[i] - bf2f(hi));
            }
            aHi[mt][ks] = hi8;
            aLo[mt][ks] = lo8;
            if (writeH && r < NN) {
                float* op = hbn + (size_t)r * H + kb;
                *(float4*)op = make_float4(vv[0], vv[1], vv[2], vv[3]);
                *(float4*)(op + 4) = make_float4(vv[4], vv[5], vv[6], vv[7]);
            }
        }
    }
    __syncthreads();

    f4_t acc[2][8];
#pragma unroll
    for (int a = 0; a < 2; ++a)
#pragma unroll
        for (int b = 0; b < 8; ++b) acc[a][b] = (f4_t){0.f, 0.f, 0.f, 0.f};

#pragma unroll
    for (int nt = 0; nt < 8; ++nt) {
#pragma unroll
        for (int ks = 0; ks < 4; ++ks) {
            size_t lo = ((size_t)(nt * 16 + sub) * BPAD + ks * 4 + quad) * 8;
            bf8_t bHi = *(const bf8_t*)(lbHi + lo);
            bf8_t bLo = *(const bf8_t*)(lbLo + lo);
#pragma unroll
            for (int mt = 0; mt < 2; ++mt) {
                acc[mt][nt] = __builtin_amdgcn_mfma_f32_16x16x32_bf16(aHi[mt][ks], bHi, acc[mt][nt], 0, 0, 0);
                acc[mt][nt] = __builtin_amdgcn_mfma_f32_16x16x32_bf16(aLo[mt][ks], bHi, acc[mt][nt], 0, 0, 0);
                acc[mt][nt] = __builtin_amdgcn_mfma_f32_16x16x32_bf16(aHi[mt][ks], bLo, acc[mt][nt], 0, 0, 0);
            }
        }
    }

    float* outp = (table == 0) ? tab0 : (table == 1) ? tab1 : (table == 2) ? tab2 : tab3;
#pragma unroll
    for (int mt = 0; mt < 2; ++mt)
#pragma unroll
        for (int nt = 0; nt < 8; ++nt) {
            int col = nt * 16 + sub;
#pragma unroll
            for (int rr = 0; rr < 4; ++rr) {
                int row = m0 + mt * 16 + quad * 4 + rr;
                if (row < NN) outp[(size_t)row * H + col] = acc[mt][nt][rr];
            }
        }
}

// Edge-parallel segmented CSR aggregation over planar tables (unchanged R11).
__global__ __launch_bounds__(256) void agg_edge_kernel(const int4* __restrict__ csr_fe,
                                                       const int* __restrict__ csr_dst,
                                                       const float* __restrict__ Wf,
                                                       const float* __restrict__ bf,
                                                       const float* __restrict__ Ws,
                                                       const float* __restrict__ bs,
                                                       const float* __restrict__ tab0,
                                                       const float* __restrict__ tab1,
                                                       const float* __restrict__ tab2,
                                                       const float* __restrict__ tab3,
                                                       const float* __restrict__ invdeg,
                                                       float* __restrict__ h,
                                                       float* __restrict__ sum,
                                                       float* __restrict__ sumsq) {
    int tid = threadIdx.x;
    if (blockIdx.x == 0 && tid < H) { sum[tid] = 0.0f; sumsq[tid] = 0.0f; }
    int lane = tid & 63;
    int wv = tid >> 6;
    int base = (blockIdx.x * 4 + wv) * 32;
    int c0 = 2 * lane;

    const float2* Pf2 = (const float2*)tab0;
    const float2* Ps2 = (const float2*)tab1;
    const float2* Qf2 = (const float2*)tab2;
    const float2* Qs2 = (const float2*)tab3;

    float2 wf0 = *(const float2*)&Wf[256 * H + c0];
    float2 wf1 = *(const float2*)&Wf[257 * H + c0];
    float2 wf2 = *(const float2*)&Wf[258 * H + c0];
    float2 ws0 = *(const float2*)&Ws[256 * H + c0];
    float2 ws1 = *(const float2*)&Ws[257 * H + c0];
    float2 ws2 = *(const float2*)&Ws[258 * H + c0];
    float2 bf2_ = *(const float2*)&bf[c0];
    float2 bs2_ = *(const float2*)&bs[c0];

    int4 fe = csr_fe[base + (lane & 31)];
    int  dd = csr_dst[base + (lane & 31)];

    float2 qf[8], qs[8];
#pragma unroll
    for (int i = 0; i < 8; ++i) {
        int s = __builtin_amdgcn_readlane(fe.w, i);
        qf[i] = Qf2[(size_t)s * 64 + lane];
        qs[i] = Qs2[(size_t)s * 64 + lane];
    }

    int dcur = __builtin_amdgcn_readlane(dd, 0);
    float2 pfCur = Pf2[(size_t)dcur * 64 + lane];
    float2 psCur = Ps2[(size_t)dcur * 64 + lane];
    int tNext = 1;
    while (tNext < 32 && __builtin_amdgcn_readlane(dd, tNext) == dcur) ++tNext;
    int dNext = (tNext < 32) ? __builtin_amdgcn_readlane(dd, tNext) : 0;
    float2 pfNext = Pf2[(size_t)dNext * 64 + lane];
    float2 psNext = Ps2[(size_t)dNext * 64 + lane];

    float acc0 = 0.f, acc1 = 0.f;

#pragma unroll
    for (int tb = 0; tb < 32; tb += 8) {
#pragma unroll
        for (int i = 0; i < 8; ++i) {
            int t = tb + i;
            if (t == tNext) {   // wave-uniform segment boundary
                float inv = invdeg[dcur];
                atomicAdd(&h[(size_t)dcur * H + c0], acc0 * inv);
                atomicAdd(&h[(size_t)dcur * H + c0 + 1], acc1 * inv);
                acc0 = 0.f; acc1 = 0.f;
                dcur = dNext;
                pfCur = pfNext;
                psCur = psNext;
                int ts = t + 1;
                while (ts < 32 && __builtin_amdgcn_readlane(dd, ts) == dcur) ++ts;
                tNext = ts;
                if (ts < 32) {
                    dNext = __builtin_amdgcn_readlane(dd, ts);
                    pfNext = Pf2[(size_t)dNext * 64 + lane];
                    psNext = Ps2[(size_t)dNext * 64 + lane];
                }
            }
            float ex = __int_as_float(__builtin_amdgcn_readlane(fe.x, t));
            float ey = __int_as_float(__builtin_amdgcn_readlane(fe.y, t));
            float ez = __int_as_float(__builtin_amdgcn_readlane(fe.z, t));
            float2 qqf = qf[i], qqs = qs[i];
            if (t + 8 < 32) {
                int s2 = __builtin_amdgcn_readlane(fe.w, t + 8);
                qf[i] = Qf2[(size_t)s2 * 64 + lane];
                qs[i] = Qs2[(size_t)s2 * 64 + lane];
            }
            float f0 = fmaf(ex, wf0.x, fmaf(ey, wf1.x, fmaf(ez, wf2.x, pfCur.x + bf2_.x + qqf.x)));
            float v0 = fmaf(ex, ws0.x, fmaf(ey, ws1.x, fmaf(ez, ws2.x, psCur.x + bs2_.x + qqs.x)));
            float f1 = fmaf(ex, wf0.y, fmaf(ey, wf1.y, fmaf(ez, wf2.y, pfCur.y + bf2_.y + qqf.y)));
            float v1 = fmaf(ex, ws0.y, fmaf(ey, ws1.y, fmaf(ez, ws2.y, psCur.y + bs2_.y + qqs.y)));
            float sig0 = __builtin_amdgcn_rcpf(1.0f + __expf(-f0));
            float sp0  = fmaxf(v0, 0.0f) + __logf(1.0f + __expf(-fabsf(v0)));
            float sig1 = __builtin_amdgcn_rcpf(1.0f + __expf(-f1));
            float sp1  = fmaxf(v1, 0.0f) + __logf(1.0f + __expf(-fabsf(v1)));
            acc0 = fmaf(sig0, sp0, acc0);
            acc1 = fmaf(sig1, sp1, acc1);
        }
    }
    float inv = invdeg[dcur];
    atomicAdd(&h[(size_t)dcur * H + c0], acc0 * inv);
    atomicAdd(&h[(size_t)dcur * H + c0 + 1], acc1 * inv);
}

// per-column sum / sumsq; 4 independent row loads per iteration.
__global__ __launch_bounds__(H) void stats_kernel(const float* __restrict__ h,
                                                  float* __restrict__ sum,
                                                  float* __restrict__ sumsq) {
    int j = threadIdx.x;
    float s = 0.0f, ss = 0.0f;
    int n = blockIdx.x * 4;
    for (; n + 3 < NN; n += gridDim.x * 4) {
        float v0 = h[(size_t)(n + 0) * H + j];
        float v1 = h[(size_t)(n + 1) * H + j];
        float v2 = h[(size_t)(n + 2) * H + j];
        float v3 = h[(size_t)(n + 3) * H + j];
        s += (v0 + v1) + (v2 + v3);
        ss = fmaf(v0, v0, ss); ss = fmaf(v1, v1, ss);
        ss = fmaf(v2, v2, ss); ss = fmaf(v3, v3, ss);
    }
    for (; n < NN; ++n) {
        float v = h[(size_t)n * H + j];
        s += v;
        ss = fmaf(v, v, ss);
    }
    atomicAdd(&sum[j], s);
    atomicAdd(&sumsq[j], ss);
}

__global__ __launch_bounds__(H) void pool_kernel(const float* __restrict__ h,
                                                 const int* __restrict__ batch,
                                                 const float* __restrict__ sum,
                                                 const float* __restrict__ sumsq,
                                                 const float* __restrict__ gamma,
                                                 const float* __restrict__ beta,
                                                 float* __restrict__ g,
                                                 float* __restrict__ cnt) {
    int j = threadIdx.x;
    float mu  = sum[j] * (1.0f / NN);
    float var = sumsq[j] * (1.0f / NN) - mu * mu;
    float sc  = gamma[j] * rsqrtf(var + BN_EPSF);
    float sh  = beta[j] - mu * sc;
    for (int n = blockIdx.x; n < NN; n += gridDim.x) {
        int b = batch[n];
        float v = fmaf(h[(size_t)n * H + j], sc, sh);
        v = v > 0.0f ? v : 0.0f;
        atomicAdd(&g[(size_t)b * H + j], v);
        if (j == 0) atomicAdd(&cnt[b], 1.0f);
    }
}

__global__ __launch_bounds__(H) void mlp_kernel(const float* __restrict__ g,
                                                const float* __restrict__ cnt,
                                                const float* __restrict__ W1,
                                                const float* __restrict__ b1,
                                                const float* __restrict__ W2,
                                                const float* __restrict__ b2,
                                                const float* __restrict__ W3,
                                                const float* __restrict__ b3,
                                                float* __restrict__ out) {
    int gid = blockIdx.x, j = threadIdx.x;
    __shared__ float s1[H];
    __shared__ float s2[H];
    __shared__ float wsum[2];
    float c = cnt[gid];
    c = c < 1.0f ? 1.0f : c;
    s1[j] = g[gid * H + j] / c;
    __syncthreads();
    float a = b1[j];
    for (int k = 0; k < H; ++k) a = fmaf(s1[k], W1[k * H + j], a);
    a = a > 0.0f ? a : 0.0f;
    s2[j] = a;
    __syncthreads();
    float t = b2[j];
    for (int k = 0; k < H; ++k) t = fmaf(s2[k], W2[k * H + j], t);
    t = t > 0.0f ? t : 0.0f;
    float p = t * W3[j];
    for (int off = 32; off > 0; off >>= 1) p += __shfl_down(p, off, 64);
    if ((j & 63) == 0) wsum[j >> 6] = p;
    __syncthreads();
    if (j == 0) out[gid] = wsum[0] + wsum[1] + b3[0];
}

extern "C" void kernel_launch(void* const* d_in, const int* in_sizes, int n_in,
                              void* d_out, int out_size, void* d_ws, size_t ws_size,
                              hipStream_t stream) {
    const float* x     = (const float*)d_in[0];
    const int*   ei    = (const int*)d_in[1];
    const int*   srcp  = ei;        // edge_index[0] = source (x_j)
    const int*   dstp  = ei + NE;   // edge_index[1] = target (aggregation index)
    const int*   batch = (const int*)d_in[2];
    const float* ea    = (const float*)d_in[3];
    const float* Win   = (const float*)d_in[4];
    const float* bin   = (const float*)d_in[5];
    const float* Wf    = (const float*)d_in[6];
    const float* bf    = (const float*)d_in[7];
    const float* Ws    = (const float*)d_in[8];
    const float* bs    = (const float*)d_in[9];
    const float* gamma = (const float*)d_in[10];
    const float* beta  = (const float*)d_in[11];
    const float* W1    = (const float*)d_in[12];
    const float* b1    = (const float*)d_in[13];
    const float* W2    = (const float*)d_in[14];
    const float* b2    = (const float*)d_in[15];
    const float* W3    = (const float*)d_in[16];
    const float* b3    = (const float*)d_in[17];
    float* out = (float*)d_out;

    const size_t NH = (size_t)NN * H;
    float* wsp = (float*)d_ws;
    size_t off = 0;
    float* hA     = wsp + off; off += NH;
    float* hB     = wsp + off; off += NH;
    float* tab0   = wsp + off; off += NH;   // Pf
    float* tab1   = wsp + off; off += NH;   // Ps
    float* tab2   = wsp + off; off += NH;   // Qf
    float* tab3   = wsp + off; off += NH;   // Qs
    float* invdeg = wsp + off; off += NN;
    float* sum    = wsp + off; off += H;
    float* sumsq  = wsp + off; off += H;
    float* g      = wsp + off; off += (size_t)NG * H;
    float* cnt    = wsp + off; off += NG;
    off = (off + 3) & ~(size_t)3;
    float4* csr_ea4 = (float4*)(wsp + off); off += (size_t)NE * 4;
    int* degi      = (int*)(wsp + off); off += NN;
    int* counter   = (int*)(wsp + off); off += 1;
    int* cursor    = (int*)(wsp + off); off += NN;
    int* csr_dst   = (int*)(wsp + off); off += NE;
    off = (off + 3) & ~(size_t)3;
    ushort_t* Wt_hi = (ushort_t*)(wsp + off); off += (size_t)NL * 512 * H / 2;
    ushort_t* Wt_lo = (ushort_t*)(wsp + off); off += (size_t)NL * 512 * H / 2;

    // ---- CSR + weight prep (topology/weights fixed across layers) ----
    hipMemsetAsync(degi, 0, (NN + 1) * sizeof(int), stream);  // degi + counter
    deg_int_kernel<<<(NE + 255) / 256, 256, 0, stream>>>(dstp, degi);
    reserve_kernel<<<(NN + 255) / 256, 256, 0, stream>>>(degi, cursor, invdeg, counter);
    scatter_kernel<<<(NE + 255) / 256, 256, 0, stream>>>(srcp, dstp, ea, cursor, csr_ea4, csr_dst);
    wprep_kernel<<<(NL * 512 * H + 255) / 256, 256, 0, stream>>>(Wf, Ws, Wt_hi, Wt_lo);

    hin_kernel<<<NN, H, 0, stream>>>(x, Win, bin, hA);

    // ping-pong: layer 0 aggregates into hA (raw h0); layer l>=1's gemm reads
    // the previous target, writes post-BN h into the other buffer, which then
    // receives that layer's aggregation.
    float* hRead = hA;
    for (int l = 0; l < NL; ++l) {
        float* hTgt = (l == 0) ? hA : ((l & 1) ? hB : hA);
        node_gemm_mfma<<<dim3((NN + 127) / 128, 4), 256, 0, stream>>>(
            hRead, hTgt,
            Wt_hi + (size_t)l * 512 * H,
            Wt_lo + (size_t)l * 512 * H,
            sum, sumsq,
            gamma + (size_t)(l ? l - 1 : 0) * H,
            beta  + (size_t)(l ? l - 1 : 0) * H,
            l > 0, tab0, tab1, tab2, tab3);
        agg_edge_kernel<<<NE / 128, 256, 0, stream>>>((const int4*)csr_ea4, csr_dst,
                                                      Wf + (size_t)l * ZDH, bf + (size_t)l * H,
                                                      Ws + (size_t)l * ZDH, bs + (size_t)l * H,
                                                      tab0, tab1, tab2, tab3,
                                                      invdeg, hTgt, sum, sumsq);
        stats_kernel<<<512, H, 0, stream>>>(hTgt, sum, sumsq);
        hRead = hTgt;
    }

    hipMemsetAsync(g, 0, ((size_t)NG * H + NG) * sizeof(float), stream);
    pool_kernel<<<2048, H, 0, stream>>>(hRead, batch, sum, sumsq,
                                        gamma + (size_t)(NL - 1) * H,
                                        beta + (size_t)(NL - 1) * H, g, cnt);
    mlp_kernel<<<NG, H, 0, stream>>>(g, cnt, W1, b1, W2, b2, W3, b3, out);
}

// Round 13
// 542.975 us; speedup vs baseline: 1.3047x; 1.0060x over previous
//
#include <hip/hip_runtime.h>
#include <math.h>

#define NN 20000
#define NE 160000
#define NG 1000
#define IND 11
#define H 128
#define ED 3
#define NL 5
#define ZDH (259*128)
#define BN_EPSF 1e-5f
#define BPAD 17   /* 16B-chunks per B-row in LDS (16 + 1 pad) */
#define EPW 16    /* edges per wave in agg_edge */

typedef unsigned short ushort_t;
typedef __attribute__((ext_vector_type(8))) short bf8_t;
typedef __attribute__((ext_vector_type(4))) float f4_t;

__device__ inline ushort_t f2bf(float x) {
    unsigned int u = __float_as_uint(x);
    unsigned int r = (u + 0x7fffu + ((u >> 16) & 1u)) >> 16;
    return (ushort_t)r;
}
__device__ inline float bf2f(ushort_t b) {
    return __uint_as_float(((unsigned int)b) << 16);
}

// ---------------- CSR build (once per call) ----------------

__global__ void deg_int_kernel(const int* __restrict__ dst, int* __restrict__ degi) {
    int e = blockIdx.x * blockDim.x + threadIdx.x;
    if (e < NE) atomicAdd(&degi[dst[e]], 1);
}

__global__ __launch_bounds__(256) void reserve_kernel(const int* __restrict__ degi,
                                                      int* __restrict__ cursor,
                                                      float* __restrict__ invdeg,
                                                      int* __restrict__ counter) {
    int n = blockIdx.x * blockDim.x + threadIdx.x;
    int lane = threadIdx.x & 63;
    int v = (n < NN) ? degi[n] : 0;
    int x = v;
#pragma unroll
    for (int st = 1; st < 64; st <<= 1) {
        int y = __shfl_up(x, st, 64);
        if (lane >= st) x += y;
    }
    int total = __shfl(x, 63, 64);
    int base = 0;
    if (lane == 63) base = atomicAdd(counter, total);
    base = __shfl(base, 63, 64);
    if (n < NN) {
        cursor[n] = base + x - v;
        invdeg[n] = 1.0f / (float)(v < 1 ? 1 : v);
    }
}

__global__ void scatter_kernel(const int* __restrict__ src, const int* __restrict__ dst,
                               const float* __restrict__ ea,
                               int* __restrict__ cursor, float4* __restrict__ csr_ea4,
                               int* __restrict__ csr_dst) {
    int e = blockIdx.x * blockDim.x + threadIdx.x;
    if (e < NE) {
        int d = dst[e];
        int pos = atomicAdd(&cursor[d], 1);
        float4 r;
        r.x = ea[e * ED + 0];
        r.y = ea[e * ED + 1];
        r.z = ea[e * ED + 2];
        r.w = __int_as_float(src[e]);
        csr_ea4[pos] = r;
        csr_dst[pos] = d;
    }
}

// ---------------- weight prep: transpose to [n][k] bf16 hi/lo ----------------
// table order: 0=Pf(Wf k<128), 1=Ps(Ws k<128), 2=Qf(Wf k>=128), 3=Qs(Ws k>=128)
__global__ void wprep_kernel(const float* __restrict__ Wf, const float* __restrict__ Ws,
                             ushort_t* __restrict__ Wt_hi, ushort_t* __restrict__ Wt_lo) {
    int idx = blockIdx.x * 256 + threadIdx.x;   // l*65536 + n*128 + k
    if (idx >= NL * 512 * H) return;
    int k = idx & 127;
    int n = (idx >> 7) & 511;
    int l = idx >> 16;
    int t = n >> 7, j = n & 127;
    const float* W = (t == 0 || t == 2) ? Wf : Ws;
    int krow = (t < 2) ? k : (H + k);
    float v = W[(size_t)l * ZDH + krow * H + j];
    ushort_t hi = f2bf(v);
    Wt_hi[idx] = hi;
    Wt_lo[idx] = f2bf(v - bf2f(hi));
}

// ---------------- network ----------------

__global__ __launch_bounds__(H) void hin_kernel(const float* __restrict__ x,
                                                const float* __restrict__ Win,
                                                const float* __restrict__ bin,
                                                float* __restrict__ h) {
    int n = blockIdx.x;
    int j = threadIdx.x;
    __shared__ float xr[IND];
    if (j < IND) xr[j] = x[n * IND + j];
    __syncthreads();
    float acc = bin[j];
#pragma unroll
    for (int k = 0; k < IND; ++k) acc = fmaf(xr[k], Win[k * H + j], acc);
    h[(size_t)n * H + j] = acc;
}

// MFMA node GEMM v5 (unchanged from R12): B staged in LDS once per block.
__global__ __launch_bounds__(256, 2) void node_gemm_mfma(const float* __restrict__ hsrc,
                                                         float* __restrict__ hbn,
                                                         const ushort_t* __restrict__ Wt_hi,
                                                         const ushort_t* __restrict__ Wt_lo,
                                                         const float* __restrict__ sum,
                                                         const float* __restrict__ sumsq,
                                                         const float* __restrict__ gamma,
                                                         const float* __restrict__ beta,
                                                         int applyBN,
                                                         float* __restrict__ tab0,
                                                         float* __restrict__ tab1,
                                                         float* __restrict__ tab2,
                                                         float* __restrict__ tab3) {
    __shared__ __align__(16) ushort_t lbHi[128 * BPAD * 8];
    __shared__ __align__(16) ushort_t lbLo[128 * BPAD * 8];
    int table = blockIdx.y;
    int wave = threadIdx.x >> 6;
    int lane = threadIdx.x & 63;
    int sub = lane & 15;
    int quad = lane >> 4;
    int m0 = blockIdx.x * 128 + wave * 32;
    int writeH = applyBN && (table == 0);

    const ushort_t* wh = Wt_hi + (size_t)table * 128 * H;
    const ushort_t* wl = Wt_lo + (size_t)table * 128 * H;

    for (int c = threadIdx.x; c < 2048; c += 256) {
        int n = c >> 4, k = c & 15;
        bf8_t vh = *(const bf8_t*)(wh + n * H + k * 8);
        bf8_t vl = *(const bf8_t*)(wl + n * H + k * 8);
        *(bf8_t*)(lbHi + ((size_t)n * BPAD + k) * 8) = vh;
        *(bf8_t*)(lbLo + ((size_t)n * BPAD + k) * 8) = vl;
    }

    bf8_t aHi[2][4], aLo[2][4];
#pragma unroll
    for (int ks = 0; ks < 4; ++ks) {
        int kb = ks * 32 + quad * 8;
        float sc8[8], sh8[8];
        if (applyBN) {
            float4 su0 = *(const float4*)&sum[kb],   su1 = *(const float4*)&sum[kb + 4];
            float4 sq0 = *(const float4*)&sumsq[kb], sq1 = *(const float4*)&sumsq[kb + 4];
            float4 ga0 = *(const float4*)&gamma[kb], ga1 = *(const float4*)&gamma[kb + 4];
            float4 be0 = *(const float4*)&beta[kb],  be1 = *(const float4*)&beta[kb + 4];
            float su[8] = {su0.x, su0.y, su0.z, su0.w, su1.x, su1.y, su1.z, su1.w};
            float sq[8] = {sq0.x, sq0.y, sq0.z, sq0.w, sq1.x, sq1.y, sq1.z, sq1.w};
            float ga[8] = {ga0.x, ga0.y, ga0.z, ga0.w, ga1.x, ga1.y, ga1.z, ga1.w};
            float be[8] = {be0.x, be0.y, be0.z, be0.w, be1.x, be1.y, be1.z, be1.w};
#pragma unroll
            for (int i = 0; i < 8; ++i) {
                float mu  = su[i] * (1.0f / NN);
                float var = sq[i] * (1.0f / NN) - mu * mu;
                sc8[i] = ga[i] * rsqrtf(var + BN_EPSF);
                sh8[i] = be[i] - mu * sc8[i];
            }
        }
#pragma unroll
        for (int mt = 0; mt < 2; ++mt) {
            int r = m0 + mt * 16 + sub;
            int rc = r < NN ? r : NN - 1;
            const float* hp = hsrc + (size_t)rc * H + kb;
            float4 v0 = *(const float4*)hp;
            float4 v1 = *(const float4*)(hp + 4);
            float vv[8] = {v0.x, v0.y, v0.z, v0.w, v1.x, v1.y, v1.z, v1.w};
            if (applyBN) {
#pragma unroll
                for (int i = 0; i < 8; ++i) {
                    float v = fmaf(vv[i], sc8[i], sh8[i]);
                    vv[i] = v > 0.0f ? v : 0.0f;
                }
            }
            bf8_t hi8, lo8;
#pragma unroll
            for (int i = 0; i < 8; ++i) {
                ushort_t hi = f2bf(vv[i]);
                hi8[i] = (short)hi;
                lo8[i] = (short)f2bf(vv[i] - bf2f(hi));
            }
            aHi[mt][ks] = hi8;
            aLo[mt][ks] = lo8;
            if (writeH && r < NN) {
                float* op = hbn + (size_t)r * H + kb;
                *(float4*)op = make_float4(vv[0], vv[1], vv[2], vv[3]);
                *(float4*)(op + 4) = make_float4(vv[4], vv[5], vv[6], vv[7]);
            }
        }
    }
    __syncthreads();

    f4_t acc[2][8];
#pragma unroll
    for (int a = 0; a < 2; ++a)
#pragma unroll
        for (int b = 0; b < 8; ++b) acc[a][b] = (f4_t){0.f, 0.f, 0.f, 0.f};

#pragma unroll
    for (int nt = 0; nt < 8; ++nt) {
#pragma unroll
        for (int ks = 0; ks < 4; ++ks) {
            size_t lo = ((size_t)(nt * 16 + sub) * BPAD + ks * 4 + quad) * 8;
            bf8_t bHi = *(const bf8_t*)(lbHi + lo);
            bf8_t bLo = *(const bf8_t*)(lbLo + lo);
#pragma unroll
            for (int mt = 0; mt < 2; ++mt) {
                acc[mt][nt] = __builtin_amdgcn_mfma_f32_16x16x32_bf16(aHi[mt][ks], bHi, acc[mt][nt], 0, 0, 0);
                acc[mt][nt] = __builtin_amdgcn_mfma_f32_16x16x32_bf16(aLo[mt][ks], bHi, acc[mt][nt], 0, 0, 0);
                acc[mt][nt] = __builtin_amdgcn_mfma_f32_16x16x32_bf16(aHi[mt][ks], bLo, acc[mt][nt], 0, 0, 0);
            }
        }
    }

    float* outp = (table == 0) ? tab0 : (table == 1) ? tab1 : (table == 2) ? tab2 : tab3;
#pragma unroll
    for (int mt = 0; mt < 2; ++mt)
#pragma unroll
        for (int nt = 0; nt < 8; ++nt) {
            int col = nt * 16 + sub;
#pragma unroll
            for (int rr = 0; rr < 4; ++rr) {
                int row = m0 + mt * 16 + quad * 4 + rr;
                if (row < NN) outp[(size_t)row * H + col] = acc[mt][nt][rr];
            }
        }
}

// Edge-parallel segmented CSR aggregation; EPW=16 edges per wave (10000 waves
// saturate all wave slots — R12's 5000 waves capped occupancy at 44%).
__global__ __launch_bounds__(256) void agg_edge_kernel(const int4* __restrict__ csr_fe,
                                                       const int* __restrict__ csr_dst,
                                                       const float* __restrict__ Wf,
                                                       const float* __restrict__ bf,
                                                       const float* __restrict__ Ws,
                                                       const float* __restrict__ bs,
                                                       const float* __restrict__ tab0,
                                                       const float* __restrict__ tab1,
                                                       const float* __restrict__ tab2,
                                                       const float* __restrict__ tab3,
                                                       const float* __restrict__ invdeg,
                                                       float* __restrict__ h,
                                                       float* __restrict__ sum,
                                                       float* __restrict__ sumsq) {
    int tid = threadIdx.x;
    if (blockIdx.x == 0 && tid < H) { sum[tid] = 0.0f; sumsq[tid] = 0.0f; }
    int lane = tid & 63;
    int wv = tid >> 6;
    int base = (blockIdx.x * 4 + wv) * EPW;
    int c0 = 2 * lane;

    const float2* Pf2 = (const float2*)tab0;
    const float2* Ps2 = (const float2*)tab1;
    const float2* Qf2 = (const float2*)tab2;
    const float2* Qs2 = (const float2*)tab3;

    float2 wf0 = *(const float2*)&Wf[256 * H + c0];
    float2 wf1 = *(const float2*)&Wf[257 * H + c0];
    float2 wf2 = *(const float2*)&Wf[258 * H + c0];
    float2 ws0 = *(const float2*)&Ws[256 * H + c0];
    float2 ws1 = *(const float2*)&Ws[257 * H + c0];
    float2 ws2 = *(const float2*)&Ws[258 * H + c0];
    float2 bf2_ = *(const float2*)&bf[c0];
    float2 bs2_ = *(const float2*)&bs[c0];

    // lanes replicate 16 edge records 4x (broadcast reads)
    int4 fe = csr_fe[base + (lane & (EPW - 1))];
    int  dd = csr_dst[base + (lane & (EPW - 1))];

    float2 qf[8], qs[8];
#pragma unroll
    for (int i = 0; i < 8; ++i) {
        int s = __builtin_amdgcn_readlane(fe.w, i);
        qf[i] = Qf2[(size_t)s * 64 + lane];
        qs[i] = Qs2[(size_t)s * 64 + lane];
    }

    int dcur = __builtin_amdgcn_readlane(dd, 0);
    float2 pfCur = Pf2[(size_t)dcur * 64 + lane];
    float2 psCur = Ps2[(size_t)dcur * 64 + lane];
    int tNext = 1;
    while (tNext < EPW && __builtin_amdgcn_readlane(dd, tNext) == dcur) ++tNext;
    int dNext = (tNext < EPW) ? __builtin_amdgcn_readlane(dd, tNext) : 0;
    float2 pfNext = Pf2[(size_t)dNext * 64 + lane];
    float2 psNext = Ps2[(size_t)dNext * 64 + lane];

    float acc0 = 0.f, acc1 = 0.f;

#pragma unroll
    for (int tb = 0; tb < EPW; tb += 8) {
#pragma unroll
        for (int i = 0; i < 8; ++i) {
            int t = tb + i;
            if (t == tNext) {   // wave-uniform segment boundary
                float inv = invdeg[dcur];
                atomicAdd(&h[(size_t)dcur * H + c0], acc0 * inv);
                atomicAdd(&h[(size_t)dcur * H + c0 + 1], acc1 * inv);
                acc0 = 0.f; acc1 = 0.f;
                dcur = dNext;
                pfCur = pfNext;
                psCur = psNext;
                int ts = t + 1;
                while (ts < EPW && __builtin_amdgcn_readlane(dd, ts) == dcur) ++ts;
                tNext = ts;
                if (ts < EPW) {
                    dNext = __builtin_amdgcn_readlane(dd, ts);
                    pfNext = Pf2[(size_t)dNext * 64 + lane];
                    psNext = Ps2[(size_t)dNext * 64 + lane];
                }
            }
            float ex = __int_as_float(__builtin_amdgcn_readlane(fe.x, t));
            float ey = __int_as_float(__builtin_amdgcn_readlane(fe.y, t));
            float ez = __int_as_float(__builtin_amdgcn_readlane(fe.z, t));
            float2 qqf = qf[i], qqs = qs[i];
            if (t + 8 < EPW) {
                int s2 = __builtin_amdgcn_readlane(fe.w, t + 8);
                qf[i] = Qf2[(size_t)s2 * 64 + lane];
                qs[i] = Qs2[(size_t)s2 * 64 + lane];
            }
            float f0 = fmaf(ex, wf0.x, fmaf(ey, wf1.x, fmaf(ez, wf2.x, pfCur.x + bf2_.x + qqf.x)));
            float v0 = fmaf(ex, ws0.x, fmaf(ey, ws1.x, fmaf(ez, ws2.x, psCur.x + bs2_.x + qqs.x)));
            float f1 = fmaf(ex, wf0.y, fmaf(ey, wf1.y, fmaf(ez, wf2.y, pfCur.y + bf2_.y + qqf.y)));
            float v1 = fmaf(ex, ws0.y, fmaf(ey, ws1.y, fmaf(ez, ws2.y, psCur.y + bs2_.y + qqs.y)));
            float sig0 = __builtin_amdgcn_rcpf(1.0f + __expf(-f0));
            float sp0  = fmaxf(v0, 0.0f) + __logf(1.0f + __expf(-fabsf(v0)));
            float sig1 = __builtin_amdgcn_rcpf(1.0f + __expf(-f1));
            float sp1  = fmaxf(v1, 0.0f) + __logf(1.0f + __expf(-fabsf(v1)));
            acc0 = fmaf(sig0, sp0, acc0);
            acc1 = fmaf(sig1, sp1, acc1);
        }
    }
    float inv = invdeg[dcur];
    atomicAdd(&h[(size_t)dcur * H + c0], acc0 * inv);
    atomicAdd(&h[(size_t)dcur * H + c0 + 1], acc1 * inv);
}

// per-column sum / sumsq; 4 independent row loads per iteration.
__global__ __launch_bounds__(H) void stats_kernel(const float* __restrict__ h,
                                                  float* __restrict__ sum,
                                                  float* __restrict__ sumsq) {
    int j = threadIdx.x;
    float s = 0.0f, ss = 0.0f;
    int n = blockIdx.x * 4;
    for (; n + 3 < NN; n += gridDim.x * 4) {
        float v0 = h[(size_t)(n + 0) * H + j];
        float v1 = h[(size_t)(n + 1) * H + j];
        float v2 = h[(size_t)(n + 2) * H + j];
        float v3 = h[(size_t)(n + 3) * H + j];
        s += (v0 + v1) + (v2 + v3);
        ss = fmaf(v0, v0, ss); ss = fmaf(v1, v1, ss);
        ss = fmaf(v2, v2, ss); ss = fmaf(v3, v3, ss);
    }
    for (; n < NN; ++n) {
        float v = h[(size_t)n * H + j];
        s += v;
        ss = fmaf(v, v, ss);
    }
    atomicAdd(&sum[j], s);
    atomicAdd(&sumsq[j], ss);
}

__global__ __launch_bounds__(H) void pool_kernel(const float* __restrict__ h,
                                                 const int* __restrict__ batch,
                                                 const float* __restrict__ sum,
                                                 const float* __restrict__ sumsq,
                                                 const float* __restrict__ gamma,
                                                 const float* __restrict__ beta,
                                                 float* __restrict__ g,
                                                 float* __restrict__ cnt) {
    int j = threadIdx.x;
    float mu  = sum[j] * (1.0f / NN);
    float var = sumsq[j] * (1.0f / NN) - mu * mu;
    float sc  = gamma[j] * rsqrtf(var + BN_EPSF);
    float sh  = beta[j] - mu * sc;
    for (int n = blockIdx.x; n < NN; n += gridDim.x) {
        int b = batch[n];
        float v = fmaf(h[(size_t)n * H + j], sc, sh);
        v = v > 0.0f ? v : 0.0f;
        atomicAdd(&g[(size_t)b * H + j], v);
        if (j == 0) atomicAdd(&cnt[b], 1.0f);
    }
}

__global__ __launch_bounds__(H) void mlp_kernel(const float* __restrict__ g,
                                                const float* __restrict__ cnt,
                                                const float* __restrict__ W1,
                                                const float* __restrict__ b1,
                                                const float* __restrict__ W2,
                                                const float* __restrict__ b2,
                                                const float* __restrict__ W3,
                                                const float* __restrict__ b3,
                                                float* __restrict__ out) {
    int gid = blockIdx.x, j = threadIdx.x;
    __shared__ float s1[H];
    __shared__ float s2[H];
    __shared__ float wsum[2];
    float c = cnt[gid];
    c = c < 1.0f ? 1.0f : c;
    s1[j] = g[gid * H + j] / c;
    __syncthreads();
    float a = b1[j];
    for (int k = 0; k < H; ++k) a = fmaf(s1[k], W1[k * H + j], a);
    a = a > 0.0f ? a : 0.0f;
    s2[j] = a;
    __syncthreads();
    float t = b2[j];
    for (int k = 0; k < H; ++k) t = fmaf(s2[k], W2[k * H + j], t);
    t = t > 0.0f ? t : 0.0f;
    float p = t * W3[j];
    for (int off = 32; off > 0; off >>= 1) p += __shfl_down(p, off, 64);
    if ((j & 63) == 0) wsum[j >> 6] = p;
    __syncthreads();
    if (j == 0) out[gid] = wsum[0] + wsum[1] + b3[0];
}

extern "C" void kernel_launch(void* const* d_in, const int* in_sizes, int n_in,
                              void* d_out, int out_size, void* d_ws, size_t ws_size,
                              hipStream_t stream) {
    const float* x     = (const float*)d_in[0];
    const int*   ei    = (const int*)d_in[1];
    const int*   srcp  = ei;        // edge_index[0] = source (x_j)
    const int*   dstp  = ei + NE;   // edge_index[1] = target (aggregation index)
    const int*   batch = (const int*)d_in[2];
    const float* ea    = (const float*)d_in[3];
    const float* Win   = (const float*)d_in[4];
    const float* bin   = (const float*)d_in[5];
    const float* Wf    = (const float*)d_in[6];
    const float* bf    = (const float*)d_in[7];
    const float* Ws    = (const float*)d_in[8];
    const float* bs    = (const float*)d_in[9];
    const float* gamma = (const float*)d_in[10];
    const float* beta  = (const float*)d_in[11];
    const float* W1    = (const float*)d_in[12];
    const float* b1    = (const float*)d_in[13];
    const float* W2    = (const float*)d_in[14];
    const float* b2    = (const float*)d_in[15];
    const float* W3    = (const float*)d_in[16];
    const float* b3    = (const float*)d_in[17];
    float* out = (float*)d_out;

    const size_t NH = (size_t)NN * H;
    float* wsp = (float*)d_ws;
    size_t off = 0;
    float* hA     = wsp + off; off += NH;
    float* hB     = wsp + off; off += NH;
    float* tab0   = wsp + off; off += NH;   // Pf
    float* tab1   = wsp + off; off += NH;   // Ps
    float* tab2   = wsp + off; off += NH;   // Qf
    float* tab3   = wsp + off; off += NH;   // Qs
    float* invdeg = wsp + off; off += NN;
    float* sum    = wsp + off; off += H;
    float* sumsq  = wsp + off; off += H;
    float* g      = wsp + off; off += (size_t)NG * H;
    float* cnt    = wsp + off; off += NG;
    off = (off + 3) & ~(size_t)3;
    float4* csr_ea4 = (float4*)(wsp + off); off += (size_t)NE * 4;
    int* degi      = (int*)(wsp + off); off += NN;
    int* counter   = (int*)(wsp + off); off += 1;
    int* cursor    = (int*)(wsp + off); off += NN;
    int* csr_dst   = (int*)(wsp + off); off += NE;
    off = (off + 3) & ~(size_t)3;
    ushort_t* Wt_hi = (ushort_t*)(wsp + off); off += (size_t)NL * 512 * H / 2;
    ushort_t* Wt_lo = (ushort_t*)(wsp + off); off += (size_t)NL * 512 * H / 2;

    // ---- CSR + weight prep (topology/weights fixed across layers) ----
    hipMemsetAsync(degi, 0, (NN + 1) * sizeof(int), stream);  // degi + counter
    deg_int_kernel<<<(NE + 255) / 256, 256, 0, stream>>>(dstp, degi);
    reserve_kernel<<<(NN + 255) / 256, 256, 0, stream>>>(degi, cursor, invdeg, counter);
    scatter_kernel<<<(NE + 255) / 256, 256, 0, stream>>>(srcp, dstp, ea, cursor, csr_ea4, csr_dst);
    wprep_kernel<<<(NL * 512 * H + 255) / 256, 256, 0, stream>>>(Wf, Ws, Wt_hi, Wt_lo);

    hin_kernel<<<NN, H, 0, stream>>>(x, Win, bin, hA);

    float* hRead = hA;
    for (int l = 0; l < NL; ++l) {
        float* hTgt = (l == 0) ? hA : ((l & 1) ? hB : hA);
        node_gemm_mfma<<<dim3((NN + 127) / 128, 4), 256, 0, stream>>>(
            hRead, hTgt,
            Wt_hi + (size_t)l * 512 * H,
            Wt_lo + (size_t)l * 512 * H,
            sum, sumsq,
            gamma + (size_t)(l ? l - 1 : 0) * H,
            beta  + (size_t)(l ? l - 1 : 0) * H,
            l > 0, tab0, tab1, tab2, tab3);
        agg_edge_kernel<<<NE / (4 * EPW), 256, 0, stream>>>((const int4*)csr_ea4, csr_dst,
                                                            Wf + (size_t)l * ZDH, bf + (size_t)l * H,
                                                            Ws + (size_t)l * ZDH, bs + (size_t)l * H,
                                                            tab0, tab1, tab2, tab3,
                                                            invdeg, hTgt, sum, sumsq);
        stats_kernel<<<512, H, 0, stream>>>(hTgt, sum, sumsq);
        hRead = hTgt;
    }

    hipMemsetAsync(g, 0, ((size_t)NG * H + NG) * sizeof(float), stream);
    pool_kernel<<<2048, H, 0, stream>>>(hRead, batch, sum, sumsq,
                                        gamma + (size_t)(NL - 1) * H,
                                        beta + (size_t)(NL - 1) * H, g, cnt);
    mlp_kernel<<<NG, H, 0, stream>>>(g, cnt, W1, b1, W2, b2, W3, b3, out);
}